// Round 9
// baseline (980.597 us; speedup 1.0000x reference)
//
#include <hip/hip_runtime.h>

#define B_ 256
#define T_ 2048
#define H_ 64
#define MB 16              // batch rows per block (one MFMA M-tile)
#define NBLK (B_ / MB)     // 16 blocks

typedef float f32x4 __attribute__((ext_vector_type(4)));
typedef _Float16 h16x4 __attribute__((ext_vector_type(4)));

__device__ __forceinline__ float fast_sigmoid(float v) {
    float e = __builtin_amdgcn_exp2f(-1.4426950408889634f * v);
    return __builtin_amdgcn_rcpf(1.0f + e);
}
__device__ __forceinline__ float fast_tanh(float v) {
    float e = __builtin_amdgcn_exp2f(2.8853900817779268f * v);
    return fmaf(-2.0f, __builtin_amdgcn_rcpf(1.0f + e), 1.0f);
}

// MFMA-based GRU step. Block = 16 batch rows, 4 waves. Wave w owns output
// channels [16w,16w+16) for ALL 3 gates (r,z,n) -> per-lane gate alignment,
// activations fully in-register, zero gate exchange. Weights live as MFMA
// B-fragments (12 x v4h = 24 regs/lane) -- MFMA sources AGPR/VGPR natively,
// so register residency is free (no v_accvgpr_read copies, the R2-R8 tax).
// h: fp32 carried in regs (ho[4], matches C-layout rows); f16 copy in LDS
// hbuf (double-buffered) feeds next step's A-fragments. One barrier/step.
// Fragment layout (v_mfma_f32_16x16x16f16, classic gfx908 mapping):
//   A[m][k]: m = lane&15, k = 4*(lane>>4)+j (j=0..3)
//   B[k][n]: n = lane&15, k = 4*(lane>>4)+j
//   C[m][n]: n = lane&15, m = 4*(lane>>4)+i (i=0..3)  [m89-verified geometry]
// Any within-lane k-permutation error cancels: A and B use the SAME mapping.
__global__ __launch_bounds__(256, 1) __attribute__((amdgpu_waves_per_eu(1, 1)))
void gru_kernel(const float* __restrict__ x,
                const float* __restrict__ W_ih,
                const float* __restrict__ W_hh,
                const float* __restrict__ b_ih,
                const float* __restrict__ b_hh,
                float* __restrict__ out)
{
    __shared__ _Float16 hbuf[2][MB][68];   // [buf][batch][chan], row 136B (b64-aligned)
    __shared__ float    xls[64][MB];       // [t2][batch] x-tile for this 64-step block
    __shared__ float    obuf[MB][65];      // [batch][t2] staged h[..][63] (+1 pad)

    const int tid  = threadIdx.x;
    const int lane = tid & 63;
    const int w    = tid >> 6;
    const int ln15 = lane & 15;
    const int g    = lane >> 4;
    const int b0   = blockIdx.x * MB;
    const int c    = w * 16 + ln15;        // my output channel (0..63)

    // ---- B-fragments: wb[gate][kt], W_hh[gate*64+c][kt*16 + 4g .. +3] ----
    h16x4 wb[3][4];
    #pragma unroll
    for (int gam = 0; gam < 3; ++gam) {
        #pragma unroll
        for (int kt = 0; kt < 4; ++kt) {
            const float* p = W_hh + (size_t)(gam * 64 + c) * H_ + kt * 16 + 4 * g;
            wb[gam][kt] = h16x4{(_Float16)p[0], (_Float16)p[1],
                                (_Float16)p[2], (_Float16)p[3]};
        }
    }
    #pragma unroll
    for (int gam = 0; gam < 3; ++gam)
        #pragma unroll
        for (int kt = 0; kt < 4; ++kt)
            asm volatile("" : "+v"(wb[gam][kt]));   // keep resident, block remat

    // per-channel x-side params
    const float wihr = W_ih[c];
    const float wihz = W_ih[64 + c];
    const float wihn = W_ih[128 + c];
    const float br   = b_ih[c]       + b_hh[c];
    const float bz   = b_ih[64 + c]  + b_hh[64 + c];
    const float bhn  = b_hh[128 + c];
    const float bin  = b_ih[128 + c];

    // ---- init h = 0, stage x-tile for tb=0 ----
    for (int idx = tid; idx < MB * 68; idx += 256)
        ((_Float16*)hbuf[0])[idx] = (_Float16)0.0f;
    #pragma unroll
    for (int k = 0; k < 4; ++k) {
        int idx = tid + k * 256;
        int r = idx >> 6, cc = idx & 63;
        xls[cc][r] = x[(size_t)(b0 + r) * T_ + cc];
    }
    float ho[4] = {0.f, 0.f, 0.f, 0.f};    // fp32 h for (batch 4g+i, chan c)
    __syncthreads();

    for (int tb = 0; tb < T_ / 64; ++tb) {
        #pragma unroll 2
        for (int t2 = 0; t2 < 64; ++t2) {
            const int pb = t2 & 1;

            // x for my 4 batch rows (broadcast b128, conflict-free)
            f32x4 xq = *(const f32x4*)&xls[t2][4 * g];

            // A-fragments from hbuf[pb]: row ln15, k = 4g + 16kt + j
            h16x4 af[4];
            #pragma unroll
            for (int kt = 0; kt < 4; ++kt)
                af[kt] = *(const h16x4*)&hbuf[pb][ln15][kt * 16 + 4 * g];

            // 12 MFMA: 3 gates x 4 K-tiles, fp32 accumulate
            f32x4 accr = {0.f,0.f,0.f,0.f};
            f32x4 accz = {0.f,0.f,0.f,0.f};
            f32x4 accn = {0.f,0.f,0.f,0.f};
            #pragma unroll
            for (int kt = 0; kt < 4; ++kt) {
                accr = __builtin_amdgcn_mfma_f32_16x16x16f16(af[kt], wb[0][kt], accr, 0, 0, 0);
                accz = __builtin_amdgcn_mfma_f32_16x16x16f16(af[kt], wb[1][kt], accz, 0, 0, 0);
                accn = __builtin_amdgcn_mfma_f32_16x16x16f16(af[kt], wb[2][kt], accn, 0, 0, 0);
            }

            // activations: 4 independent batch rows per lane
            #pragma unroll
            for (int i = 0; i < 4; ++i) {
                float xi = xq[i];
                float r  = fast_sigmoid(accr[i] + fmaf(xi, wihr, br));
                float z  = fast_sigmoid(accz[i] + fmaf(xi, wihz, bz));
                float n  = fast_tanh(fmaf(r, accn[i] + bhn, fmaf(xi, wihn, bin)));
                float h  = n + z * (ho[i] - n);          // (1-z)*n + z*h
                ho[i] = h;
                hbuf[pb ^ 1][4 * g + i][c] = (_Float16)h; // publish for next step
                if (c == 63) obuf[4 * g + i][t2] = h;     // stage output channel
            }
            __syncthreads();
        }

        // flush output block (coalesced), restage x for next 64 steps
        #pragma unroll
        for (int k = 0; k < 4; ++k) {
            int idx = tid + k * 256;
            int r = idx >> 6, cc = idx & 63;
            out[(size_t)(b0 + r) * T_ + tb * 64 + cc] = obuf[r][cc];
        }
        if (tb + 1 < T_ / 64) {
            #pragma unroll
            for (int k = 0; k < 4; ++k) {
                int idx = tid + k * 256;
                int r = idx >> 6, cc = idx & 63;
                xls[cc][r] = x[(size_t)(b0 + r) * T_ + (tb + 1) * 64 + cc];
            }
        }
        __syncthreads();   // protect obuf reuse + xls visibility
    }
}

extern "C" void kernel_launch(void* const* d_in, const int* in_sizes, int n_in,
                              void* d_out, int out_size, void* d_ws, size_t ws_size,
                              hipStream_t stream) {
    const float* x    = (const float*)d_in[0];
    const float* W_ih = (const float*)d_in[1];
    const float* W_hh = (const float*)d_in[2];
    const float* b_ih = (const float*)d_in[3];
    const float* b_hh = (const float*)d_in[4];
    float* out = (float*)d_out;

    dim3 grid(NBLK), block(256);
    gru_kernel<<<grid, block, 0, stream>>>(x, W_ih, W_hh, b_ih, b_hh, out);
}

// Round 10
// 807.801 us; speedup vs baseline: 1.2139x; 1.2139x over previous
//
#include <hip/hip_runtime.h>

#define B_ 256
#define T_ 2048
#define H_ 64

typedef float f32x4 __attribute__((ext_vector_type(4)));
typedef _Float16 h16x4 __attribute__((ext_vector_type(4)));
typedef _Float16 h16x8 __attribute__((ext_vector_type(8)));

#if __has_builtin(__builtin_amdgcn_mfma_f32_16x16x32_f16)
#define HAS_K32 1
#else
#define HAS_K32 0
#endif

__device__ __forceinline__ float readlane_f(float v, int idx) {
    return __builtin_bit_cast(float,
        __builtin_amdgcn_readlane(__builtin_bit_cast(int, v), idx));
}

#define NLOG2E (-1.4426950408889634f)   // -log2(e): sigmoid prescale
#define TLOG2E ( 2.8853900817779268f)   // 2*log2(e): tanh prescale

// SINGLE WAVE per batch row (zero barriers -- measured best structure) with
// M=1-degenerate MFMA replacing the 96 dot2s. Every lane loads the SAME h
// into its A-fragment, so all 16 C-rows are identical copies and EVERY lane
// ends up holding the gate pre-activations for its 4 channels
// {ln15,16+ln15,32+ln15,48+ln15} -- activations spread over all 64 lanes,
// no exchange. Weights are MFMA B-operands: AGPR-native residency, the
// v_accvgpr copy tax of R2-R8 is structurally impossible. 24 MFMAs
// (16x16x32, 12 independent 2-chains) = ~120 issue cyc vs 192 for dot2.
// exp2 scale factors folded into weights/biases at preload.
// Layout note: A and B fragments are indexed by the same (lane,slot)
// formula, so any within-slot k-permutation of the true HW mapping cancels
// in the contraction (validated: R9 passed with this reasoning).
__global__ __launch_bounds__(64, 1)
void gru_kernel(const float* __restrict__ x,
                const float* __restrict__ W_ih,
                const float* __restrict__ W_hh,
                const float* __restrict__ b_ih,
                const float* __restrict__ b_hh,
                float* __restrict__ out)
{
    __shared__ __align__(16) _Float16 shh[H_];

    const int lane = threadIdx.x;
    const int ln15 = lane & 15;
    const int kg   = lane >> 4;          // k-slot group
    const int b    = blockIdx.x;

    // ---- B-fragments: wb[gate][ntile][ktile], prescaled ----
#if HAS_K32
    h16x8 wb[3][4][2];
    #pragma unroll
    for (int g = 0; g < 3; ++g) {
        const float s = (g == 2) ? TLOG2E : NLOG2E;
        #pragma unroll
        for (int nt = 0; nt < 4; ++nt) {
            #pragma unroll
            for (int kt = 0; kt < 2; ++kt) {
                const float* p = W_hh + (size_t)(g * 64 + nt * 16 + ln15) * H_
                               + kt * 32 + 8 * kg;
                h16x8 v;
                #pragma unroll
                for (int j = 0; j < 8; ++j) v[j] = (_Float16)(s * p[j]);
                wb[g][nt][kt] = v;
            }
        }
    }
#else
    h16x4 wb[3][4][4];
    #pragma unroll
    for (int g = 0; g < 3; ++g) {
        const float s = (g == 2) ? TLOG2E : NLOG2E;
        #pragma unroll
        for (int nt = 0; nt < 4; ++nt) {
            #pragma unroll
            for (int kt = 0; kt < 4; ++kt) {
                const float* p = W_hh + (size_t)(g * 64 + nt * 16 + ln15) * H_
                               + kt * 16 + 4 * kg;
                wb[g][nt][kt] = h16x4{(_Float16)(s * p[0]), (_Float16)(s * p[1]),
                                      (_Float16)(s * p[2]), (_Float16)(s * p[3])};
            }
        }
    }
#endif

    // ---- x-side params for my 4 channels (chan = 16s + ln15), prescaled ----
    float xwr[4], xbr[4], xwz[4], xbz[4], xwn[4], xbn[4], bhn[4];
    #pragma unroll
    for (int s = 0; s < 4; ++s) {
        const int c = 16 * s + ln15;
        xwr[s] = NLOG2E * W_ih[c];
        xbr[s] = NLOG2E * (b_ih[c] + b_hh[c]);
        xwz[s] = NLOG2E * W_ih[64 + c];
        xbz[s] = NLOG2E * (b_ih[64 + c] + b_hh[64 + c]);
        xwn[s] = TLOG2E * W_ih[128 + c];
        xbn[s] = TLOG2E * b_ih[128 + c];
        bhn[s] = TLOG2E * b_hh[128 + c];
    }

    const float* __restrict__ xrow = x + (size_t)b * T_;
    float* __restrict__ orow = out + (size_t)b * T_;

    shh[lane] = (_Float16)0.0f;          // h0 = 0 (single wave: in-order LDS)

    float ho[4] = {0.f, 0.f, 0.f, 0.f};  // fp32 h for my 4 channels
    float oval  = 0.0f;
    float xa = xrow[lane];
    float xb = 0.0f;
    const f32x4 z4 = {0.f, 0.f, 0.f, 0.f};

    for (int tb = 0; tb < T_ / 64; ++tb) {
        if (tb < T_ / 64 - 1) xb = xrow[(tb + 1) * 64 + lane];

        #pragma unroll 4
        for (int t2 = 0; t2 < 64; ++t2) {
            const float xt = readlane_f(xa, t2);
            float xpr[4], xpz[4], xpn[4];
            #pragma unroll
            for (int s = 0; s < 4; ++s) {
                xpr[s] = fmaf(xt, xwr[s], xbr[s]);
                xpz[s] = fmaf(xt, xwz[s], xbz[s]);
                xpn[s] = fmaf(xt, xwn[s], xbn[s]);
            }

            f32x4 accr[4], accz[4], accn[4];
#if HAS_K32
            h16x8 a0 = *(const h16x8*)&shh[8 * kg];        // k-slots 0..31
            h16x8 a1 = *(const h16x8*)&shh[32 + 8 * kg];   // k-slots 32..63
            #pragma unroll
            for (int nt = 0; nt < 4; ++nt) {
                accr[nt] = __builtin_amdgcn_mfma_f32_16x16x32_f16(a0, wb[0][nt][0], z4, 0, 0, 0);
                accz[nt] = __builtin_amdgcn_mfma_f32_16x16x32_f16(a0, wb[1][nt][0], z4, 0, 0, 0);
                accn[nt] = __builtin_amdgcn_mfma_f32_16x16x32_f16(a0, wb[2][nt][0], z4, 0, 0, 0);
            }
            #pragma unroll
            for (int nt = 0; nt < 4; ++nt) {
                accr[nt] = __builtin_amdgcn_mfma_f32_16x16x32_f16(a1, wb[0][nt][1], accr[nt], 0, 0, 0);
                accz[nt] = __builtin_amdgcn_mfma_f32_16x16x32_f16(a1, wb[1][nt][1], accz[nt], 0, 0, 0);
                accn[nt] = __builtin_amdgcn_mfma_f32_16x16x32_f16(a1, wb[2][nt][1], accn[nt], 0, 0, 0);
            }
#else
            h16x4 af[4];
            #pragma unroll
            for (int kt = 0; kt < 4; ++kt)
                af[kt] = *(const h16x4*)&shh[16 * kt + 4 * kg];
            #pragma unroll
            for (int nt = 0; nt < 4; ++nt) {
                accr[nt] = __builtin_amdgcn_mfma_f32_16x16x16f16(af[0], wb[0][nt][0], z4, 0, 0, 0);
                accz[nt] = __builtin_amdgcn_mfma_f32_16x16x16f16(af[0], wb[1][nt][0], z4, 0, 0, 0);
                accn[nt] = __builtin_amdgcn_mfma_f32_16x16x16f16(af[0], wb[2][nt][0], z4, 0, 0, 0);
            }
            #pragma unroll
            for (int kt = 1; kt < 4; ++kt) {
                #pragma unroll
                for (int nt = 0; nt < 4; ++nt) {
                    accr[nt] = __builtin_amdgcn_mfma_f32_16x16x16f16(af[kt], wb[0][nt][kt], accr[nt], 0, 0, 0);
                    accz[nt] = __builtin_amdgcn_mfma_f32_16x16x16f16(af[kt], wb[1][nt][kt], accz[nt], 0, 0, 0);
                    accn[nt] = __builtin_amdgcn_mfma_f32_16x16x16f16(af[kt], wb[2][nt][kt], accn[nt], 0, 0, 0);
                }
            }
#endif

            // ---- activations: my 4 channels (row 0 copy = element 0) ----
            float hnew[4];
            #pragma unroll
            for (int s = 0; s < 4; ++s) {
                float r  = __builtin_amdgcn_rcpf(
                               1.0f + __builtin_amdgcn_exp2f(accr[s][0] + xpr[s]));
                float zg = __builtin_amdgcn_rcpf(
                               1.0f + __builtin_amdgcn_exp2f(accz[s][0] + xpz[s]));
                float pre = fmaf(r, accn[s][0] + bhn[s], xpn[s]);
                float n  = fmaf(-2.0f, __builtin_amdgcn_rcpf(
                               1.0f + __builtin_amdgcn_exp2f(pre)), 1.0f);
                float h  = fmaf(zg, ho[s] - n, n);   // (1-z)*n + z*h
                ho[s]   = h;
                hnew[s] = h;
            }

            // publish h (lanes 0-15 cover all 64 channels; banks 8s+ln15/2 -> clean)
            if (lane < 16) {
                #pragma unroll
                for (int s = 0; s < 4; ++s)
                    shh[16 * s + ln15] = (_Float16)hnew[s];
            }

            float h63 = readlane_f(hnew[3], 15);     // chan 63 = s3 @ ln15==15
            oval = (t2 == lane) ? h63 : oval;        // latch out[t]
        }

        orow[tb * 64 + lane] = oval;                 // coalesced 256B store
        xa = xb;
    }
}

extern "C" void kernel_launch(void* const* d_in, const int* in_sizes, int n_in,
                              void* d_out, int out_size, void* d_ws, size_t ws_size,
                              hipStream_t stream) {
    const float* x    = (const float*)d_in[0];
    const float* W_ih = (const float*)d_in[1];
    const float* W_hh = (const float*)d_in[2];
    const float* b_ih = (const float*)d_in[3];
    const float* b_hh = (const float*)d_in[4];
    float* out = (float*)d_out;

    dim3 grid(B_), block(64);
    gru_kernel<<<grid, block, 0, stream>>>(x, W_ih, W_hh, b_ih, b_hh, out);
}

// Round 11
// 619.917 us; speedup vs baseline: 1.5818x; 1.3031x over previous
//
#include <hip/hip_runtime.h>

#define B_ 256
#define T_ 2048
#define H_ 64

typedef float f32x4 __attribute__((ext_vector_type(4)));
typedef _Float16 h16x2 __attribute__((ext_vector_type(2)));

__device__ __forceinline__ float fdot2(h16x2 a, h16x2 b, float c) {
#if __has_builtin(__builtin_amdgcn_fdot2)
    return __builtin_amdgcn_fdot2(a, b, c, false);   // v_dot2_f32_f16
#else
    float d;
    asm("v_dot2_f32_f16 %0, %1, %2, %3" : "=v"(d) : "v"(a), "v"(b), "v"(c));
    return d;
#endif
}

__device__ __forceinline__ float readlane_f(float v, int idx) {
    return __builtin_bit_cast(float,
        __builtin_amdgcn_readlane(__builtin_bit_cast(int, v), idx));
}

#define NLOG2E (-1.4426950408889634f)   // -log2(e): sigmoid prescale
#define TLOG2E ( 2.8853900817779268f)   // 2*log2(e): tanh prescale

// R7 structure (single wave / row, zero barriers, f16 dot2) with critical-
// path surgery:
//  - dots issued in gate order r -> z -> n: r's sigmoid latency hides under
//    z's dot issue; z's sigmoid hides under n's dots + tanh; the final
//    h_new fma waits on neither.
//  - exp2 prescales folded into the f16 weights / x-side constants at
//    preload: sigmoid = rcp(1+exp2(s)), tanh = 1-2*rcp(1+exp2(s)) with s
//    coming straight off the (prescaled) dot -- no multiply at the head of
//    any transcendental chain.
//  - h published (cvt + ds_write_b16) immediately after h_new so the next
//    step's 8x ds_read_b128 turnaround starts ASAP; output latch afterwards.
__global__ __launch_bounds__(64, 1)
void gru_kernel(const float* __restrict__ x,
                const float* __restrict__ W_ih,
                const float* __restrict__ W_hh,
                const float* __restrict__ b_ih,
                const float* __restrict__ b_hh,
                float* __restrict__ out)
{
    __shared__ __align__(16) _Float16 shh[H_];

    const int lane = threadIdx.x;
    const int b    = blockIdx.x;

    // ---- preload W_hh rows {lane, 64+lane, 128+lane}, prescale, cvt f16 ----
    h16x2 wr[32], wz[32], wn[32];
    {
        const f32x4* pr = (const f32x4*)(W_hh + (size_t)lane * H_);
        const f32x4* pz = (const f32x4*)(W_hh + (size_t)(64 + lane) * H_);
        const f32x4* pn = (const f32x4*)(W_hh + (size_t)(128 + lane) * H_);
        #pragma unroll
        for (int q = 0; q < 16; ++q) {
            f32x4 vr = pr[q], vz = pz[q], vn = pn[q];
            wr[2*q]   = h16x2{(_Float16)(NLOG2E * vr.x), (_Float16)(NLOG2E * vr.y)};
            wr[2*q+1] = h16x2{(_Float16)(NLOG2E * vr.z), (_Float16)(NLOG2E * vr.w)};
            wz[2*q]   = h16x2{(_Float16)(NLOG2E * vz.x), (_Float16)(NLOG2E * vz.y)};
            wz[2*q+1] = h16x2{(_Float16)(NLOG2E * vz.z), (_Float16)(NLOG2E * vz.w)};
            wn[2*q]   = h16x2{(_Float16)(TLOG2E * vn.x), (_Float16)(TLOG2E * vn.y)};
            wn[2*q+1] = h16x2{(_Float16)(TLOG2E * vn.z), (_Float16)(TLOG2E * vn.w)};
        }
    }
    #pragma unroll
    for (int i = 0; i < 32; ++i)
        asm volatile("" : "+v"(wr[i]), "+v"(wz[i]), "+v"(wn[i]));

    // x-side params, prescaled
    const float wihr = NLOG2E * W_ih[lane];
    const float wihz = NLOG2E * W_ih[64 + lane];
    const float wihn = TLOG2E * W_ih[128 + lane];
    const float br   = NLOG2E * (b_ih[lane]      + b_hh[lane]);
    const float bz   = NLOG2E * (b_ih[64 + lane] + b_hh[64 + lane]);
    const float bhn  = TLOG2E * b_hh[128 + lane];
    const float bin  = TLOG2E * b_ih[128 + lane];

    const float* __restrict__ xrow = x + (size_t)b * T_;
    float* __restrict__ orow = out + (size_t)b * T_;

    shh[lane] = (_Float16)0.0f;      // h0 = 0 (single wave: in-order LDS)

    float h_own = 0.0f;
    float oval  = 0.0f;
    float xa = xrow[lane];           // current 64-step block of x
    float xb = 0.0f;

    for (int tb = 0; tb < T_ / 64; ++tb) {
        if (tb < T_ / 64 - 1) xb = xrow[(tb + 1) * 64 + lane];

        #pragma unroll 4
        for (int t2 = 0; t2 < 64; ++t2) {
            const float xt  = readlane_f(xa, t2);
            const float xpr = fmaf(xt, wihr, br);
            const float xpz = fmaf(xt, wihz, bz);
            const float xpn = fmaf(xt, wihn, bin);

            // ---- h: 8 broadcast ds_read_b128 (64 f16 = 128 B) ----
            h16x2 hh[32];
            const f32x4* hp = (const f32x4*)shh;
            #pragma unroll
            for (int q = 0; q < 8; ++q) {
                union { f32x4 f; h16x2 h[4]; } u;
                u.f = hp[q];
                hh[4*q]   = u.h[0];
                hh[4*q+1] = u.h[1];
                hh[4*q+2] = u.h[2];
                hh[4*q+3] = u.h[3];
            }

            // ---- r-gate dots FIRST: its sigmoid hides under z/n issue ----
            float ar[4] = {0,0,0,0};
            #pragma unroll
            for (int i = 0; i < 32; ++i) ar[i >> 3] = fdot2(wr[i], hh[i], ar[i >> 3]);
            float sr = ((ar[0] + ar[1]) + (ar[2] + ar[3])) + xpr;
            float r  = __builtin_amdgcn_rcpf(1.0f + __builtin_amdgcn_exp2f(sr));

            // ---- z-gate dots second: sigmoid hides under n dots + tanh ----
            float az[4] = {0,0,0,0};
            #pragma unroll
            for (int i = 0; i < 32; ++i) az[i >> 3] = fdot2(wz[i], hh[i], az[i >> 3]);
            float sz = ((az[0] + az[1]) + (az[2] + az[3])) + xpz;
            float z  = __builtin_amdgcn_rcpf(1.0f + __builtin_amdgcn_exp2f(sz));

            // ---- n-gate dots last ----
            float an[4] = {0,0,0,0};
            #pragma unroll
            for (int i = 0; i < 32; ++i) an[i >> 3] = fdot2(wn[i], hh[i], an[i >> 3]);
            float hn  = ((an[0] + an[1]) + (an[2] + an[3])) + bhn;
            float pre = fmaf(r, hn, xpn);
            float n   = fmaf(-2.0f, __builtin_amdgcn_rcpf(
                              1.0f + __builtin_amdgcn_exp2f(pre)), 1.0f);

            float h_new = fmaf(z, h_own - n, n);   // (1-z)*n + z*h
            h_own = h_new;

            // publish FIRST: next step's read turnaround starts now
            shh[lane] = (_Float16)h_new;

            // output latch (off critical path)
            float h63 = readlane_f(h_new, 63);
            oval = (t2 == lane) ? h63 : oval;
        }

        orow[tb * 64 + lane] = oval;               // coalesced 256B store
        xa = xb;
    }
}

extern "C" void kernel_launch(void* const* d_in, const int* in_sizes, int n_in,
                              void* d_out, int out_size, void* d_ws, size_t ws_size,
                              hipStream_t stream) {
    const float* x    = (const float*)d_in[0];
    const float* W_ih = (const float*)d_in[1];
    const float* W_hh = (const float*)d_in[2];
    const float* b_ih = (const float*)d_in[3];
    const float* b_hh = (const float*)d_in[4];
    float* out = (float*)d_out;

    dim3 grid(B_), block(64);
    gru_kernel<<<grid, block, 0, stream>>>(x, W_ih, W_hh, b_ih, b_hh, out);
}